// Round 15
// baseline (23.625 us; speedup 1.0000x reference)
//
#include <hip/hip_runtime.h>

// Problem constants
#define NSTEPS 255
#define NTRAJ  16384
#define NBLK   256          // integration blocks; 64 trajectories each
#define CH     15           // steps per prefetch chunk; 17*15 = 255

#define GAMMA_F 0.36f
#define OMEGA_F 5.0265f
#define DT_F    0.00390625f          // 2^-8
#define CW      0.0375f              // sqrt(GAMMA)*sqrt(DT) = 0.6/16 (exact)
#define GD      (GAMMA_F * DT_F)
#define OD      (OMEGA_F * DT_F)

// LDS state history (R7/R9-validated): [slot][lane] fp16x4, pitch 520 B.
#define PITCH  520
#define STATEB 132608        // 255*520 = 132600, padded

typedef __fp16 half2v __attribute__((ext_vector_type(2)));
typedef float  f32x2  __attribute__((ext_vector_type(2)));

__device__ __forceinline__ unsigned pk2(float a, float b) {
  half2v h = __builtin_amdgcn_cvt_pkrtz(a, b);
  return __builtin_bit_cast(unsigned, h);
}

// One Euler-Maruyama step (R4/R7/R9-validated math, bit-identical).
#define STEP2(wx_, wy_, ii_) {                                                  \
  const float w0 = (wx_) * CW;                                                  \
  const float cy = (wy_) * CW;                                                  \
  const f32x2 sw = __builtin_shufflevector(v, v, 1, 0);    /* (y,x) */          \
  f32x2 t = __builtin_elementwise_fma(epack, sw, v);                            \
  t = __builtin_elementwise_fma(mGD2, v, t);                                    \
  const f32x2 w0s = {w0, w0};                                                   \
  t = __builtin_elementwise_fma(-(v * z), w0s, t);                              \
  const f32x2 cys = {-cy, cy};                                                  \
  t = __builtin_elementwise_fma(sw, cys, t);                                    \
  t[1] = __builtin_fmaf(-OD, z, t[1]);                                          \
  const float a_ = __builtin_fmaf(OD, v[1], z);                                 \
  const float r_ = __builtin_fmaf(-(z * z), w0, w0);                            \
  v = t; z = a_ + r_;                                                           \
  *(uint2*)(sb + (ii_) * PITCH) = make_uint2(pk2(v[0], v[1]), pk2(z, 0.0f));    \
}

#define LOADC(BUF, CHUNK_) {                                                    \
  _Pragma("unroll")                                                             \
  for (int i_ = 0; i_ < CH; ++i_) BUF[i_] = wrow[(CHUNK_) * CH + i_];           \
}

#define PROC(BUF) {                                                             \
  _Pragma("unroll")                                                             \
  for (int i_ = 0; i_ < CH; ++i_) STEP2((BUF)[i_].x, (BUF)[i_].y, i_)           \
  sb += CH * PITCH;                                                             \
}

// grid = 256 blocks x 64 threads (1 wave); block g owns trajectories g*64..+63.
// R9-validated loop + tail; partial layout TRANSPOSED to [slot][vb][3] so the
// finalize read is contiguous. Tail stores are scattered 12B (fire-and-forget).
__global__ __launch_bounds__(64) void sde_integrate(const float* __restrict__ inp,
                                                    const float* __restrict__ wvec,
                                                    float* __restrict__ partial) {
  __shared__ alignas(16) char smem[STATEB];
  const int g = blockIdx.x, l = threadIdx.x;
  // trajectory n = g*64+l; eps = inputs[n % 32] = inputs[l & 31]
  const float eps = inp[l & 31];
  const f32x2 epack = {-eps * DT_F, eps * DT_F};
  const f32x2 mGD2  = {-GD, -GD};

  const float2* __restrict__ wrow =
      reinterpret_cast<const float2*>(wvec) + (size_t)(g * 64 + l) * NSTEPS;
  char* sb = smem + l * 8;             // slot 0, this lane's column

  f32x2 v = {0.0f, 0.0f};
  float z = 1.0f;

  float2 bufA[CH], bufB[CH], bufC[CH]; // static indexing only (regs)

  // prefetch distance 2: chunks c and c+1 in flight before computing c
  LOADC(bufA, 0);
  LOADC(bufB, 1);
  #pragma unroll 1
  for (int k = 0; k < 5; ++k) {        // chunks 3k..3k+2, loads 3k+2..3k+4
    LOADC(bufC, 3 * k + 2); PROC(bufA);
    LOADC(bufA, 3 * k + 3); PROC(bufB);
    LOADC(bufB, 3 * k + 4); PROC(bufC);
  }
  PROC(bufA);                          // chunk 15
  PROC(bufB);                          // chunk 16 (slots 240..254)

  __syncthreads();                     // single wave: cheap; orders LDS for tail

  // Tail (R9-validated order): lane l reduces slots l, l+64, l+128, l+192.
  #pragma unroll
  for (int k = 0; k < 4; ++k) {
    const int s = l + 64 * k;
    if (s < NSTEPS) {
      const char* rb = smem + (size_t)s * PITCH;
      f32x2 sxy = {0.0f, 0.0f};
      float fz = 0.0f;
      #pragma unroll
      for (int j = 0; j < 64; ++j) {
        const uint2 u = *(const uint2*)(rb + j * 8);
        const half2v xy = __builtin_bit_cast(half2v, u.x);
        const half2v zp = __builtin_bit_cast(half2v, u.y);
        const f32x2 vxy = {(float)xy[0], (float)xy[1]};
        sxy += vxy;
        fz += (float)zp[0];
      }
      float* p = partial + ((size_t)s * NBLK + g) * 3;   // [slot][vb][3]
      p[0] = sxy[0]; p[1] = sxy[1]; p[2] = fz;
    }
  }
}

// Finalize: thread idx -> b = idx&31, t = idx>>5. Wave reads dense, 16B-aligned
// 96B rows of partial[t-1] (coalesced 3KB lines); sums j=0..7 ascending
// (bit-identical order to R9). 128 blocks x 64 threads.
__global__ __launch_bounds__(64) void sde_finalize(const float* __restrict__ partial,
                                                   float* __restrict__ out) {
  const int idx = blockIdx.x * 64 + threadIdx.x;   // 0..8191
  const int b = idx & 31;
  const int t = idx >> 5;
  float* o = out + ((size_t)b * 256 + t) * 6;

  if (t == 0) {
    o[0] = 0.5f; o[1] = 0.5f; o[2] = 0.5f; o[3] = 0.5f;
    o[4] = 1.0f; o[5] = 0.0f;
    return;
  }

  // 24 contiguous floats = 6 aligned float4 loads
  const float4* q = reinterpret_cast<const float4*>(
      partial + ((size_t)(t - 1) * NBLK + b * 8) * 3);
  float a[24];
  #pragma unroll
  for (int i = 0; i < 6; ++i) {
    const float4 f = q[i];
    a[4 * i] = f.x; a[4 * i + 1] = f.y; a[4 * i + 2] = f.z; a[4 * i + 3] = f.w;
  }
  float sx = 0.0f, sy = 0.0f, sz = 0.0f;
  #pragma unroll
  for (int j = 0; j < 8; ++j) {        // same ascending-j order as R9
    sx += a[3 * j]; sy += a[3 * j + 1]; sz += a[3 * j + 2];
  }
  const float inv = 1.0f / 512.0f;
  const float mx = sx * inv, my = sy * inv, mz = sz * inv;
  o[0] = 0.5f * (1.0f + mx);
  o[1] = 0.5f * (1.0f - mx);
  o[2] = 0.5f * (1.0f + my);
  o[3] = 0.5f * (1.0f - my);
  o[4] = 0.5f * (1.0f + mz);
  o[5] = 0.5f * (1.0f - mz);
}

extern "C" void kernel_launch(void* const* d_in, const int* in_sizes, int n_in,
                              void* d_out, int out_size, void* d_ws, size_t ws_size,
                              hipStream_t stream) {
  (void)in_sizes; (void)n_in; (void)out_size; (void)ws_size;
  const float* inp  = (const float*)d_in[0];   // [32]
  const float* wvec = (const float*)d_in[1];   // [16384][255][2]
  float* out     = (float*)d_out;              // [32][256][6]
  float* partial = (float*)d_ws;               // [255][256][3] f32 = 783360 B

  sde_integrate<<<NBLK, 64, 0, stream>>>(inp, wvec, partial);
  sde_finalize<<<128, 64, 0, stream>>>(partial, out);
}